// Round 4
// baseline (15075.517 us; speedup 1.0000x reference)
//
#include <hip/hip_runtime.h>
#include <hip/hip_bf16.h>

// ================= Design (round 4 = round 3 + fence-free barriers) =================
// 8 independent groups of 32 batch rows; 32 blocks/group (1/CU). Two per-group
// barriers per step. r3 lesson: REL/ACQ agent atomics emit buffer_wbl2/buffer_inv
// -> 512 full-L2 flush walks per step dominated (25.8us/step, MfmaUtil 1.4%).
// r4: communicated data (h', acat) uses RELAXED agent-scope atomics (sc0 sc1
// write-through stores, cache-bypassing loads); barrier = syncthreads (vmcnt
// drain) + relaxed fetch_add + relaxed spin. NO cache maintenance anywhere.
// Weights keep plain loads -> stay L2-resident (no more per-step invalidation).

#define NBLK 256
#define NTHR 512

typedef __attribute__((ext_vector_type(8))) short bf16x8;
typedef __attribute__((ext_vector_type(4))) float f32x4;
typedef __hip_bfloat16 bf16;

// ---------------- workspace layout (bytes) ----------------
#define WS_BAR     0ull        // 8 grp x 1024 slots x u32 = 32768
#define WS_BS      32768ull    // 512 i32
#define WS_OFF     34816ull    // 512 i32
#define WS_BIASQ0  36864ull    // 2048 f32 (b_ih+b_hh, q=4j+g)
#define WS_BIASQF  45056ull    // 2048 f32 (+ W_ih . p1b2)
#define WS_BCAT    53248ull    // 1536 f32
#define WS_B2CAT   59392ull    // 272 f32 (257 + zero pad)
#define WS_C0      61440ull    // 256*512 f32
#define WS_H       585728ull   // 2*256*512 bf16
#define WS_ACAT    1110016ull  // 2*256*1536 bf16 (a1|a2|o1)
#define WS_WQF     2682880ull  // 2048*1024 bf16: [Whh row | Wfold row], q=4j+g
#define WS_W1CAT   6877184ull  // 1536*512 bf16 (p1_W1;p2_W1;oW1)
#define WS_W2CAT   8450048ull  // 272*512 bf16 (p1_W2;p2_W2;oW2;zeros)
// end ~8.73 MB

__device__ __forceinline__ float sigm(float x) { return 1.0f / (1.0f + __expf(-x)); }
__device__ __forceinline__ unsigned short f2bu(float x) {
  bf16 b = __float2bfloat16(x);
  return *(unsigned short*)&b;
}

// coherent (sc0 sc1) 16B load as two relaxed 8B atomic loads; union -> reg pair
__device__ __forceinline__ bf16x8 ld8c(const short* p) {
  union { unsigned long long u[2]; bf16x8 v; } t;
  t.u[0] = __hip_atomic_load((const unsigned long long*)p, __ATOMIC_RELAXED,
                             __HIP_MEMORY_SCOPE_AGENT);
  t.u[1] = __hip_atomic_load((const unsigned long long*)(p + 4), __ATOMIC_RELAXED,
                             __HIP_MEMORY_SCOPE_AGENT);
  return t.v;
}
// coherent 4B write-through store
__device__ __forceinline__ void st4c(short* p, unsigned v) {
  __hip_atomic_store((unsigned*)p, v, __ATOMIC_RELAXED, __HIP_MEMORY_SCOPE_AGENT);
}

// ---------------- staging kernels ----------------
// WQF: row q=4j+g: [Whh[orig] (512) | Wfold[orig] (512)], Wfold = Wih @ p1W2
__global__ void k_fold(char* ws, const float* __restrict__ Wih, const float* __restrict__ Whh,
                       const float* __restrict__ bih, const float* __restrict__ bhh,
                       const float* __restrict__ p1W2, const float* __restrict__ p1b2) {
  const int q = blockIdx.x;            // 0..2047
  const int j = q >> 2, g = q & 3;
  const int orig = g * 512 + j;
  __shared__ float wih[128];
  if (threadIdx.x < 128) wih[threadIdx.x] = Wih[orig * 128 + threadIdx.x];
  __syncthreads();
  bf16* Wq = (bf16*)(ws + WS_WQF);
  for (int k = threadIdx.x; k < 512; k += 256)
    Wq[(size_t)q * 1024 + k] = __float2bfloat16(Whh[orig * 512 + k]);
  for (int m = threadIdx.x; m < 512; m += 256) {
    float s = 0.f;
    for (int o = 0; o < 128; ++o) s += wih[o] * p1W2[o * 512 + m];
    Wq[(size_t)q * 1024 + 512 + m] = __float2bfloat16(s);
  }
  if (threadIdx.x == 0) {
    float b0 = bih[orig] + bhh[orig];
    ((float*)(ws + WS_BIASQ0))[q] = b0;
    float s = 0.f;
    for (int o = 0; o < 128; ++o) s += wih[o] * p1b2[o];
    ((float*)(ws + WS_BIASQF))[q] = b0 + s;
  }
}

__global__ void k_w1cat(char* ws, const float* w1a, const float* b1a, const float* w1b,
                        const float* b1b, const float* w1c, const float* b1c) {
  const int r = blockIdx.x;            // 0..1535
  const int m = r & 511;
  const float* src = (r < 512) ? w1a : ((r < 1024) ? w1b : w1c);
  const float* bsrc = (r < 512) ? b1a : ((r < 1024) ? b1b : b1c);
  bf16* W = (bf16*)(ws + WS_W1CAT);
  for (int k = threadIdx.x; k < 512; k += 256)
    W[(size_t)r * 512 + k] = __float2bfloat16(src[m * 512 + k]);
  if (threadIdx.x == 0) ((float*)(ws + WS_BCAT))[r] = bsrc[m];
}

__global__ void k_w2cat(char* ws, const float* w2a, const float* b2a, const float* w2b,
                        const float* b2b, const float* w2c, const float* b2c) {
  const int r = blockIdx.x;            // 0..271
  bf16* W = (bf16*)(ws + WS_W2CAT);
  float* bb = (float*)(ws + WS_B2CAT);
  const float* src = nullptr; const float* bsrc = nullptr; int m = 0;
  if (r < 128)      { src = w2a; bsrc = b2a; m = r; }
  else if (r < 256) { src = w2b; bsrc = b2b; m = r - 128; }
  else if (r == 256){ src = w2c; bsrc = b2c; m = 0; }
  for (int k = threadIdx.x; k < 512; k += 256)
    W[(size_t)r * 512 + k] = src ? __float2bfloat16(src[m * 512 + k]) : __float2bfloat16(0.f);
  if (threadIdx.x == 0) bb[r] = src ? bsrc[m] : 0.f;
}

__global__ void k_h0c0(char* ws, const float* __restrict__ features,
                       const float* __restrict__ Wf2h, const float* __restrict__ bf2h_) {
  const int r = blockIdx.x;            // 0..255
  __shared__ float feat[256];
  feat[threadIdx.x] = features[r * 256 + threadIdx.x];
  __syncthreads();
  float* C0 = (float*)(ws + WS_C0);
  bf16* H0 = (bf16*)(ws + WS_H);       // parity 0
  for (int n = threadIdx.x; n < 1024; n += 256) {
    float s = bf2h_[n];
    for (int k = 0; k < 256; ++k) s += Wf2h[n * 256 + k] * feat[k];
    const int j = n >> 1;
    if (n & 1) C0[r * 512 + j] = s;
    else       H0[(size_t)r * 512 + j] = __float2bfloat16(s);
  }
}

__global__ void k_bs(char* ws, const int* __restrict__ lengths) {
  __shared__ int sl[256];
  __shared__ int sbs[512];
  const int t = threadIdx.x;
  if (t < 256) sl[t] = lengths[t];
  __syncthreads();
  int c = 0;
  for (int b = 0; b < 256; ++b) c += (sl[b] > t) ? 1 : 0;
  sbs[t] = c;
  ((int*)(ws + WS_BS))[t] = c;
  __syncthreads();
  int o = 0;
  for (int u = 0; u < t; ++u) o += sbs[u];
  ((int*)(ws + WS_OFF))[t] = o;
}

// ---------------- output-phase GEMM (off-chain, runs in barrier window) ----------------
__device__ __forceinline__ void do_outs(int tm1, const short* __restrict__ Acur, int R0,
                                        int rt2, int l15, int l16, int tile,
                                        const short* __restrict__ W2, const float* __restrict__ b2cat,
                                        const int* __restrict__ bsarr, const int* __restrict__ offarr,
                                        float* __restrict__ out, int N) {
  const int kb = tile < 8 ? 0 : (tile < 16 ? 512 : 1024);
  const int wrow = tile * 16 + l15;    // <= 271 (zero-padded rows past 256)
  const short* ar = Acur + (size_t)(R0 + rt2 * 16 + l15) * 1536 + kb + l16 * 8;
  const short* wr = W2 + (size_t)wrow * 512 + l16 * 8;
  f32x4 acc = {0.f, 0.f, 0.f, 0.f};
#pragma unroll
  for (int kk = 0; kk < 16; ++kk) {
    bf16x8 av = ld8c(ar + kk * 32);
    bf16x8 bv = *(const bf16x8*)(wr + kk * 32);
    acc = __builtin_amdgcn_mfma_f32_16x16x32_bf16(av, bv, acc, 0, 0, 0);
  }
  const float bb = b2cat[wrow];
  const int bsz = bsarr[tm1], base = offarr[tm1];
  const int col = tile * 16 + l15;
  float* out_p1 = out;
  float* out_p2 = out + (size_t)N * 128;
  float* out_of = out + (size_t)N * 256;
  float* out_xx = out + (size_t)N * 257;
#pragma unroll
  for (int r = 0; r < 4; ++r) {
    const int R = R0 + rt2 * 16 + l16 * 4 + r;
    if (R < bsz) {
      const float v = acc[r] + bb;
      const size_t orow = (size_t)(base + R);
      if (col < 128)      { out_p1[orow * 128 + col] = v; out_xx[orow * 128 + col] = v; }
      else if (col < 256) { out_p2[orow * 128 + col - 128] = v; }
      else if (l15 == 0)  { out_of[orow] = v; }
    }
  }
}

// ---------------- main persistent scan kernel ----------------
__global__ void __launch_bounds__(NTHR) scan_kernel(char* ws, const int* __restrict__ lengths,
                                                    float* __restrict__ out, int N) {
  extern __shared__ char smem[];               // [0,131072): gates W slice; then 32x64 f32
  float* ldsg = (float*)(smem + 131072);

  const int bid = blockIdx.x, tid = threadIdx.x;
  const int grp = bid >> 5, lb = bid & 31;
  const int R0 = grp * 32;
  const int wave = tid >> 6, lane = tid & 63;
  const int l15 = lane & 15, l16 = lane >> 4;

  unsigned* barG = (unsigned*)(ws + WS_BAR) + grp * 1024;
  const int* bsarr = (const int*)(ws + WS_BS);
  const int* offarr = (const int*)(ws + WS_OFF);
  const float* biasq0 = (const float*)(ws + WS_BIASQ0);
  const float* biasqF = (const float*)(ws + WS_BIASQF);
  const float* bcat = (const float*)(ws + WS_BCAT);
  const float* b2cat = (const float*)(ws + WS_B2CAT);
  const float* C0 = (const float*)(ws + WS_C0);
  short* Hb = (short*)(ws + WS_H);             // [2][256][512]
  short* Ab = (short*)(ws + WS_ACAT);          // [2][256][1536]
  const short* WQF = (const short*)(ws + WS_WQF);
  const short* W1 = (const short*)(ws + WS_W1CAT);
  const short* W2 = (const short*)(ws + WS_W2CAT);

  // prologue: stage gates weight slice into LDS, XOR-swizzled. 64 rows x 2048B.
  for (int idx = tid; idx < 8192; idx += NTHR) {
    const int r = idx >> 7, c = idx & 127;
    int4 v = *(const int4*)(WQF + ((size_t)(64 * lb + r) * 1024 + c * 8));
    *(int4*)(smem + (r * 2048 + ((c * 16) ^ ((r & 7) << 4)))) = v;
  }
  const int Lr = tid >> 4, lj = tid & 15;
  float c_reg = C0[(R0 + Lr) * 512 + lb * 16 + lj];
  float b0_[4], bF_[4];
#pragma unroll
  for (int g = 0; g < 4; ++g) {
    const int q = lb * 64 + lj * 4 + g;
    b0_[g] = biasq0[q];
    bF_[g] = biasqF[q];
  }
  const int Lg = lengths[R0];                  // lengths sorted desc -> group max
  const int ct = wave & 3, rt = wave >> 2;     // phase-A wave tile
  __syncthreads();

  for (int t = 0; t < Lg; ++t) {
    const int par = t & 1, parn = par ^ 1;
    const short* Hcur = Hb + par * (256 * 512);
    const short* Acur = Ab + par * (256 * 1536);

    // ---- phase A: gates = Whh.h + Wfold.a1 (K=1024), per wave one 16x16 tile ----
    f32x4 acc = {0.f, 0.f, 0.f, 0.f};
    {
      const int lq = ct * 16 + l15;
      const char* wb = smem + lq * 2048;
      const int xr = (lq & 7) << 4;
      const short* ar = Hcur + (size_t)(R0 + rt * 16 + l15) * 512 + l16 * 8;
#pragma unroll 8
      for (int kk = 0; kk < 16; ++kk) {
        bf16x8 av = ld8c(ar + kk * 32);
        bf16x8 bv = *(const bf16x8*)(wb + ((kk * 64 + l16 * 16) ^ xr));
        acc = __builtin_amdgcn_mfma_f32_16x16x32_bf16(av, bv, acc, 0, 0, 0);
      }
      if (t > 0) {
        const short* ar2 = Acur + (size_t)(R0 + rt * 16 + l15) * 1536 + l16 * 8;
#pragma unroll 8
        for (int kk = 0; kk < 16; ++kk) {
          bf16x8 av = ld8c(ar2 + kk * 32);
          bf16x8 bv = *(const bf16x8*)(wb + (((kk + 16) * 64 + l16 * 16) ^ xr));
          acc = __builtin_amdgcn_mfma_f32_16x16x32_bf16(av, bv, acc, 0, 0, 0);
        }
      }
    }
#pragma unroll
    for (int r = 0; r < 4; ++r)
      ldsg[(rt * 16 + l16 * 4 + r) * 64 + ct * 16 + l15] = acc[r];
    __syncthreads();

    // ---- pointwise LSTM, c in register, h' -> H[parn] (write-through) ----
    {
      const float* gv = ldsg + Lr * 64 + lj * 4;
      const float gi = gv[0] + (t ? bF_[0] : b0_[0]);
      const float gf = gv[1] + (t ? bF_[1] : b0_[1]);
      const float gg = gv[2] + (t ? bF_[2] : b0_[2]);
      const float go = gv[3] + (t ? bF_[3] : b0_[3]);
      c_reg = sigm(gf) * c_reg + sigm(gi) * tanhf(gg);
      const float h = sigm(go) * tanhf(c_reg);
      const float hp = __shfl_xor(h, 1);
      if ((lj & 1) == 0) {
        const unsigned v = (unsigned)f2bu(h) | ((unsigned)f2bu(hp) << 16);
        st4c(Hb + parn * (256 * 512) + (size_t)(R0 + Lr) * 512 + lb * 16 + lj, v);
      }
    }

    // ---- arrive A: syncthreads drains vmcnt (sc1 stores at coherence point) ----
    __syncthreads();
    if (tid == 0)
      __hip_atomic_fetch_add(&barG[t * 2], 1u, __ATOMIC_RELAXED, __HIP_MEMORY_SCOPE_AGENT);

    // ---- off-chain outputs for step t-1 (overlap with barrier wait) ----
    if (t > 0 && lb < 17 && wave < 2)
      do_outs(t - 1, Acur, R0, wave, l15, l16, lb, W2, b2cat, bsarr, offarr, out, N);

    // ---- wait A (relaxed spin; no cache maintenance) ----
    if (tid == 0) {
      while (__hip_atomic_load(&barG[t * 2], __ATOMIC_RELAXED, __HIP_MEMORY_SCOPE_AGENT) < 32u)
        __builtin_amdgcn_s_sleep(1);
    }
    __syncthreads();

    // ---- phase B: acat = tanh(W1cat . h' + b), 48 cols/block, 6 wave tiles ----
    if (wave < 6) {
      const int ct3 = wave % 3, rt3 = wave / 3;
      const int cb = lb * 48 + ct3 * 16;
      const short* hr = Hb + parn * (256 * 512) + (size_t)(R0 + rt3 * 16 + l15) * 512 + l16 * 8;
      const short* wr = W1 + (size_t)(cb + l15) * 512 + l16 * 8;
      f32x4 a3 = {0.f, 0.f, 0.f, 0.f};
#pragma unroll 8
      for (int kk = 0; kk < 16; ++kk) {
        bf16x8 av = ld8c(hr + kk * 32);
        bf16x8 bv = *(const bf16x8*)(wr + kk * 32);
        a3 = __builtin_amdgcn_mfma_f32_16x16x32_bf16(av, bv, a3, 0, 0, 0);
      }
      const float bb = bcat[cb + l15];
      short* aout = Ab + parn * (256 * 1536);
#pragma unroll
      for (int r = 0; r < 4; ++r) {
        const float v = tanhf(a3[r] + bb);
        const float vp = __shfl_xor(v, 1);
        if ((l15 & 1) == 0) {
          const unsigned pv = (unsigned)f2bu(v) | ((unsigned)f2bu(vp) << 16);
          st4c(aout + (size_t)(R0 + rt3 * 16 + l16 * 4 + r) * 1536 + cb + l15, pv);
        }
      }
    }

    // ---- barrier B (a1 visible for next gates) ----
    __syncthreads();
    if (tid == 0) {
      __hip_atomic_fetch_add(&barG[t * 2 + 1], 1u, __ATOMIC_RELAXED, __HIP_MEMORY_SCOPE_AGENT);
      while (__hip_atomic_load(&barG[t * 2 + 1], __ATOMIC_RELAXED, __HIP_MEMORY_SCOPE_AGENT) < 32u)
        __builtin_amdgcn_s_sleep(1);
    }
    __syncthreads();
  }

  // epilogue: outputs for the final step (a-cat parity Lg&1, written by last phase B)
  if (lb < 17 && wave < 2)
    do_outs(Lg - 1, Ab + (Lg & 1) * (256 * 1536), R0, wave, l15, l16, lb, W2, b2cat,
            bsarr, offarr, out, N);
}

// ---------------- host ----------------
extern "C" void kernel_launch(void* const* d_in, const int* in_sizes, int n_in,
                              void* d_out, int out_size, void* d_ws, size_t ws_size,
                              hipStream_t stream) {
  const float* features = (const float*)d_in[0];
  const int* lengths = (const int*)d_in[1];
  const float* Wf2h = (const float*)d_in[2];
  const float* bf2h_ = (const float*)d_in[3];
  const float* Wih = (const float*)d_in[4];
  const float* Whh = (const float*)d_in[5];
  const float* bih = (const float*)d_in[6];
  const float* bhh = (const float*)d_in[7];
  const float* p1W1 = (const float*)d_in[8];
  const float* p1b1 = (const float*)d_in[9];
  const float* p1W2 = (const float*)d_in[10];
  const float* p1b2 = (const float*)d_in[11];
  const float* p2W1 = (const float*)d_in[12];
  const float* p2b1 = (const float*)d_in[13];
  const float* p2W2 = (const float*)d_in[14];
  const float* p2b2 = (const float*)d_in[15];
  const float* oW1 = (const float*)d_in[16];
  const float* ob1 = (const float*)d_in[17];
  const float* oW2 = (const float*)d_in[18];
  const float* ob2 = (const float*)d_in[19];

  char* ws = (char*)d_ws;
  float* outp = (float*)d_out;
  int N = out_size / 385;

  hipMemsetAsync(ws + WS_BAR, 0, 32768, stream);
  k_fold<<<2048, 256, 0, stream>>>(ws, Wih, Whh, bih, bhh, p1W2, p1b2);
  k_w1cat<<<1536, 256, 0, stream>>>(ws, p1W1, p1b1, p2W1, p2b1, oW1, ob1);
  k_w2cat<<<272, 256, 0, stream>>>(ws, p1W2, p1b2, p2W2, p2b2, oW2, ob2);
  k_h0c0<<<256, 256, 0, stream>>>(ws, features, Wf2h, bf2h_);
  k_bs<<<1, 512, 0, stream>>>(ws, lengths);

  hipFuncSetAttribute((const void*)scan_kernel,
                      hipFuncAttributeMaxDynamicSharedMemorySize, 139264);

  const int* lenv = lengths;
  void* args[] = {&ws, &lenv, &outp, &N};
  hipLaunchCooperativeKernel((const void*)scan_kernel, dim3(NBLK), dim3(NTHR),
                             args, 139264, stream);
}

// Round 6
// 6226.884 us; speedup vs baseline: 2.4210x; 2.4210x over previous
//
#include <hip/hip_runtime.h>
#include <hip/hip_bf16.h>

// ================= Design (round 6 = round 5, swizzle removed, H double-buffered) =================
// 8 independent groups of 32 batch rows; 32 blocks/group (1/CU). Two per-group
// fence-free barriers per step (relaxed agent atomics; sc write-through data).
// Coalesced staging of h'/a1 into LINEAR act LDS tile, row stride 2096B
// (2048+48: bank rotation 12 -> 2-way conflicts = free, no XOR -> removes r5's
// prime bug suspect). Gate weights (Whh|Wfold) register-resident, K-split 2-way,
// partials combined via padded ldsg[2][32][68]. W1/W2 fragment-reordered in ws.
// H double-buffered again (removes r5's second suspect). do_outs on waves 6-7.

#define NBLK 256
#define NTHR 512
#define ACT_STRIDE 2096

typedef __attribute__((ext_vector_type(8))) short bf16x8;
typedef __attribute__((ext_vector_type(4))) float f32x4;
typedef __hip_bfloat16 bf16;
typedef unsigned long long u64;

// ---------------- workspace layout (bytes) ----------------
#define WS_BAR     0ull        // 8 grp x 1024 slots x u32
#define WS_BS      32768ull    // 512 i32
#define WS_OFF     34816ull    // 512 i32
#define WS_BIASQ0  36864ull    // 2048 f32
#define WS_BIASQF  45056ull    // 2048 f32
#define WS_BCAT    53248ull    // 1536 f32
#define WS_B2CAT   59392ull    // 272 f32
#define WS_C0      61440ull    // 256*512 f32
#define WS_H       585728ull   // 2*256*512 bf16 (parity)
#define WS_ACAT    1110016ull  // 2*256*1536 bf16 (a1|a2|o1), parity
#define WS_WQF     2682880ull  // 2048*1024 bf16: [Whh row | Wfold row], q=4j+g
#define WS_W1T     6877184ull  // 1536*512 bf16, fragment-ordered
#define WS_W2T     8450048ull  // 272*512 bf16, fragment-ordered (zero pad)
// end 8728576 (~8.7 MB, same footprint as r3 which fit)

// LDS: act 32 rows x 2096B = 67072 ; ldsg[2][32][68] f32 = 17408 -> 84480
#define LDSG_OFF   67072
#define DYN_LDS    84480

__device__ __forceinline__ float sigm(float x) { return 1.0f / (1.0f + __expf(-x)); }
__device__ __forceinline__ unsigned short f2bu(float x) {
  bf16 b = __float2bfloat16(x);
  return *(unsigned short*)&b;
}
__device__ __forceinline__ u64 ld8a(const void* p) {
  return __hip_atomic_load((const u64*)p, __ATOMIC_RELAXED, __HIP_MEMORY_SCOPE_AGENT);
}
__device__ __forceinline__ bf16x8 ld16a(const short* p) {
  union { u64 u[2]; bf16x8 v; } t;
  t.u[0] = ld8a(p);
  t.u[1] = ld8a(p + 4);
  return t.v;
}
__device__ __forceinline__ void st4c(short* p, unsigned v) {
  __hip_atomic_store((unsigned*)p, v, __ATOMIC_RELAXED, __HIP_MEMORY_SCOPE_AGENT);
}
// linear LDS A-frag read: act[row][k0..k0+8) bf16 (k0 in shorts, incl. region)
__device__ __forceinline__ bf16x8 actA(const char* smem, int row, int k0) {
  return *(const bf16x8*)(smem + row * ACT_STRIDE + k0 * 2);
}

// ---------------- staging kernels ----------------
__global__ void k_fold(char* ws, const float* __restrict__ Wih, const float* __restrict__ Whh,
                       const float* __restrict__ bih, const float* __restrict__ bhh,
                       const float* __restrict__ p1W2, const float* __restrict__ p1b2) {
  const int q = blockIdx.x;            // 0..2047, q = 4j+g
  const int j = q >> 2, g = q & 3;
  const int orig = g * 512 + j;
  __shared__ float wih[128];
  if (threadIdx.x < 128) wih[threadIdx.x] = Wih[orig * 128 + threadIdx.x];
  __syncthreads();
  bf16* Wq = (bf16*)(ws + WS_WQF);
  for (int k = threadIdx.x; k < 512; k += 256)
    Wq[(size_t)q * 1024 + k] = __float2bfloat16(Whh[orig * 512 + k]);
  for (int m = threadIdx.x; m < 512; m += 256) {
    float s = 0.f;
    for (int o = 0; o < 128; ++o) s += wih[o] * p1W2[o * 512 + m];
    Wq[(size_t)q * 1024 + 512 + m] = __float2bfloat16(s);
  }
  if (threadIdx.x == 0) {
    float b0 = bih[orig] + bhh[orig];
    ((float*)(ws + WS_BIASQ0))[q] = b0;
    float s = 0.f;
    for (int o = 0; o < 128; ++o) s += wih[o] * p1b2[o];
    ((float*)(ws + WS_BIASQF))[q] = b0 + s;
  }
}

// W1T fragment order: idx = (((c16*16 + kk)*16 + l15)*4 + l16)*8 + jj
__global__ void k_w1t(char* ws, const float* w1a, const float* b1a, const float* w1b,
                      const float* b1b, const float* w1c, const float* b1c) {
  const int r = blockIdx.x;            // 0..1535 (global col)
  const int m = r & 511;
  const float* src = (r < 512) ? w1a : ((r < 1024) ? w1b : w1c);
  const float* bsrc = (r < 512) ? b1a : ((r < 1024) ? b1b : b1c);
  bf16* W = (bf16*)(ws + WS_W1T);
  const int c16 = r >> 4, l15 = r & 15;
  for (int k = threadIdx.x; k < 512; k += 256) {
    const int kk = k >> 5, l16 = (k >> 3) & 3, jj = k & 7;
    const size_t dst = ((((size_t)c16 * 16 + kk) * 16 + l15) * 4 + l16) * 8 + jj;
    W[dst] = __float2bfloat16(src[m * 512 + k]);
  }
  if (threadIdx.x == 0) ((float*)(ws + WS_BCAT))[r] = bsrc[m];
}

__global__ void k_w2t(char* ws, const float* w2a, const float* b2a, const float* w2b,
                      const float* b2b, const float* w2c, const float* b2c) {
  const int r = blockIdx.x;            // 0..271
  bf16* W = (bf16*)(ws + WS_W2T);
  float* bb = (float*)(ws + WS_B2CAT);
  const float* src = nullptr; const float* bsrc = nullptr; int m = 0;
  if (r < 128)      { src = w2a; bsrc = b2a; m = r; }
  else if (r < 256) { src = w2b; bsrc = b2b; m = r - 128; }
  else if (r == 256){ src = w2c; bsrc = b2c; m = 0; }
  const int t16 = r >> 4, l15 = r & 15;
  for (int k = threadIdx.x; k < 512; k += 256) {
    const int kk = k >> 5, l16 = (k >> 3) & 3, jj = k & 7;
    const size_t dst = ((((size_t)t16 * 16 + kk) * 16 + l15) * 4 + l16) * 8 + jj;
    W[dst] = src ? __float2bfloat16(src[m * 512 + k]) : __float2bfloat16(0.f);
  }
  if (threadIdx.x == 0) bb[r] = src ? bsrc[m] : 0.f;
}

__global__ void k_h0c0(char* ws, const float* __restrict__ features,
                       const float* __restrict__ Wf2h, const float* __restrict__ bf2h_) {
  const int r = blockIdx.x;            // 0..255
  __shared__ float feat[256];
  feat[threadIdx.x] = features[r * 256 + threadIdx.x];
  __syncthreads();
  float* C0 = (float*)(ws + WS_C0);
  bf16* H0 = (bf16*)(ws + WS_H);       // parity 0
  for (int n = threadIdx.x; n < 1024; n += 256) {
    float s = bf2h_[n];
    for (int k = 0; k < 256; ++k) s += Wf2h[n * 256 + k] * feat[k];
    const int j = n >> 1;
    if (n & 1) C0[r * 512 + j] = s;
    else       H0[(size_t)r * 512 + j] = __float2bfloat16(s);
  }
}

__global__ void k_bs(char* ws, const int* __restrict__ lengths) {
  __shared__ int sl[256];
  __shared__ int sbs[512];
  const int t = threadIdx.x;
  if (t < 256) sl[t] = lengths[t];
  __syncthreads();
  int c = 0;
  for (int b = 0; b < 256; ++b) c += (sl[b] > t) ? 1 : 0;
  sbs[t] = c;
  ((int*)(ws + WS_BS))[t] = c;
  __syncthreads();
  int o = 0;
  for (int u = 0; u < t; ++u) o += sbs[u];
  ((int*)(ws + WS_OFF))[t] = o;
}

// coalesced stage: 32 rows x 512 bf16 global -> LDS act region (linear)
__device__ __forceinline__ void stage_tile(char* smem, const short* gsrc, int rowstride,
                                           int R0, int ofs, int tid) {
  u64 v[8];
#pragma unroll
  for (int it = 0; it < 8; ++it) {
    const int c = tid + it * 512;
    const int row = c >> 7, cc = c & 127;
    v[it] = ld8a(gsrc + (size_t)(R0 + row) * rowstride + cc * 4);
  }
#pragma unroll
  for (int it = 0; it < 8; ++it) {
    const int c = tid + it * 512;
    const int row = c >> 7, cc = c & 127;
    *(u64*)(smem + row * ACT_STRIDE + ofs + cc * 8) = v[it];
  }
}

// ---------------- output GEMM (waves 6-7 during phase B) ----------------
__device__ __forceinline__ void do_outs(int tm1, const short* __restrict__ Acur, int R0,
                                        int rt2, int l15, int l16, int tile,
                                        const short* __restrict__ W2T, const float* __restrict__ b2cat,
                                        const int* __restrict__ bsarr, const int* __restrict__ offarr,
                                        float* __restrict__ out, int N) {
  const int kb = tile < 8 ? 0 : (tile < 16 ? 512 : 1024);
  const short* ar = Acur + (size_t)(R0 + rt2 * 16 + l15) * 1536 + kb + l16 * 8;
  f32x4 acc = {0.f, 0.f, 0.f, 0.f};
#pragma unroll
  for (int kk = 0; kk < 16; ++kk) {
    bf16x8 av = ld16a(ar + kk * 32);
    bf16x8 bv = *(const bf16x8*)(W2T + ((((size_t)tile * 16 + kk) * 16 + l15) * 4 + l16) * 8);
    acc = __builtin_amdgcn_mfma_f32_16x16x32_bf16(av, bv, acc, 0, 0, 0);
  }
  const int wrow = tile * 16 + l15;
  const float bb = b2cat[wrow];
  const int bsz = bsarr[tm1], base = offarr[tm1];
  const int col = wrow;
  float* out_p1 = out;
  float* out_p2 = out + (size_t)N * 128;
  float* out_of = out + (size_t)N * 256;
  float* out_xx = out + (size_t)N * 257;
#pragma unroll
  for (int r = 0; r < 4; ++r) {
    const int R = R0 + rt2 * 16 + l16 * 4 + r;
    if (R < bsz) {
      const float v = acc[r] + bb;
      const size_t orow = (size_t)(base + R);
      if (col < 128)      { out_p1[orow * 128 + col] = v; out_xx[orow * 128 + col] = v; }
      else if (col < 256) { out_p2[orow * 128 + col - 128] = v; }
      else if (l15 == 0)  { out_of[orow] = v; }
    }
  }
}

// ---------------- main persistent scan kernel ----------------
__global__ void __launch_bounds__(NTHR) scan_kernel(char* ws, const int* __restrict__ lengths,
                                                    float* __restrict__ out, int N) {
  extern __shared__ char smem[];
  float* ldsg = (float*)(smem + LDSG_OFF);     // [2][32][68] f32

  const int bid = blockIdx.x, tid = threadIdx.x;
  const int grp = bid >> 5, lb = bid & 31;
  const int R0 = grp * 32;
  const int wave = tid >> 6, lane = tid & 63;
  const int l15 = lane & 15, l16 = lane >> 4;

  unsigned* barG = (unsigned*)(ws + WS_BAR) + grp * 1024;
  const int* bsarr = (const int*)(ws + WS_BS);
  const int* offarr = (const int*)(ws + WS_OFF);
  const float* biasq0 = (const float*)(ws + WS_BIASQ0);
  const float* biasqF = (const float*)(ws + WS_BIASQF);
  const float* bcat = (const float*)(ws + WS_BCAT);
  const float* b2cat = (const float*)(ws + WS_B2CAT);
  const float* C0 = (const float*)(ws + WS_C0);
  short* Hb = (short*)(ws + WS_H);             // [2][256][512]
  short* Ab = (short*)(ws + WS_ACAT);          // [2][256][1536]
  const short* WQF = (const short*)(ws + WS_WQF);
  const short* W1T = (const short*)(ws + WS_W1T);
  const short* W2T = (const short*)(ws + WS_W2T);

  // phase-A wave task: ct = col-tile (16 q-cols), khalf = K half (0:Whh*h, 1:Wfold*a1)
  const int ct = wave & 3, khalf = wave >> 2;
  const int qb = lb * 64;
  // phase-B wave task (waves 0-5): 3 col-tiles x 2 row-tiles
  const int ct3 = (wave < 6) ? (wave % 3) : 0;
  const int rt3 = (wave < 6) ? (wave / 3) : 0;
  const int cb = lb * 48 + ct3 * 16;

  // ---- prologue ----
  stage_tile(smem, Hb, 512, R0, 0, tid);       // h0 (parity 0) -> act[:, 0:512]

  bf16x8 bfrA[16];                             // gates weights, register-resident
#pragma unroll
  for (int kk = 0; kk < 16; ++kk)
    bfrA[kk] = *(const bf16x8*)(WQF + (size_t)(qb + ct * 16 + l15) * 1024 +
                                khalf * 512 + kk * 32 + l16 * 8);
  bf16x8 bfrB[16];                             // W1 frags (waves 0-5)
  if (wave < 6) {
    const int cb16 = lb * 3 + ct3;
#pragma unroll
    for (int kk = 0; kk < 16; ++kk)
      bfrB[kk] = *(const bf16x8*)(W1T + ((((size_t)cb16 * 16 + kk) * 16 + l15) * 4 + l16) * 8);
  }
  const float bbB = (wave < 6) ? bcat[cb + l15] : 0.f;

  const int Lr = tid >> 4, lj = tid & 15;
  float c_reg = C0[(R0 + Lr) * 512 + lb * 16 + lj];
  float b0_[4], bF_[4];
#pragma unroll
  for (int g = 0; g < 4; ++g) {
    const int q = qb + lj * 4 + g;
    b0_[g] = biasq0[q];
    bF_[g] = biasqF[q];
  }
  const int Lg = lengths[R0];
  __syncthreads();

  for (int t = 0; t < Lg; ++t) {
    const int par = t & 1, parn = par ^ 1;

    // ---- phase A: gates partials (K-split), A from LDS, B from registers ----
    f32x4 acc0 = {0.f, 0.f, 0.f, 0.f}, acc1 = {0.f, 0.f, 0.f, 0.f};
    if (!(t == 0 && khalf == 1)) {
#pragma unroll
      for (int kk = 0; kk < 16; ++kk) {
        const int k0 = khalf * 512 + kk * 32 + l16 * 8;
        bf16x8 a0 = actA(smem, l15, k0);
        bf16x8 a1v = actA(smem, 16 + l15, k0);
        acc0 = __builtin_amdgcn_mfma_f32_16x16x32_bf16(a0, bfrA[kk], acc0, 0, 0, 0);
        acc1 = __builtin_amdgcn_mfma_f32_16x16x32_bf16(a1v, bfrA[kk], acc1, 0, 0, 0);
      }
    }
    {
      float* lg = ldsg + khalf * 2176;
#pragma unroll
      for (int r = 0; r < 4; ++r) {
        lg[(l16 * 4 + r) * 68 + ct * 16 + l15] = acc0[r];
        lg[(16 + l16 * 4 + r) * 68 + ct * 16 + l15] = acc1[r];
      }
    }
    __syncthreads();

    // ---- pointwise LSTM: sum K-partials + bias; c in reg; h' -> Hb[parn] ----
    {
      const float* g0 = ldsg + Lr * 68 + lj * 4;
      const float* g1 = ldsg + 2176 + Lr * 68 + lj * 4;
      const float gi = g0[0] + g1[0] + (t ? bF_[0] : b0_[0]);
      const float gf = g0[1] + g1[1] + (t ? bF_[1] : b0_[1]);
      const float gg = g0[2] + g1[2] + (t ? bF_[2] : b0_[2]);
      const float go = g0[3] + g1[3] + (t ? bF_[3] : b0_[3]);
      c_reg = sigm(gf) * c_reg + sigm(gi) * tanhf(gg);
      const float h = sigm(go) * tanhf(c_reg);
      const float hp = __shfl_xor(h, 1);
      if ((lj & 1) == 0) {
        const unsigned v = (unsigned)f2bu(h) | ((unsigned)f2bu(hp) << 16);
        st4c(Hb + parn * (256 * 512) + (size_t)(R0 + Lr) * 512 + lb * 16 + lj, v);
      }
    }

    // ---- barrier A (syncthreads drains vmcnt; relaxed add + spin) ----
    __syncthreads();
    if (tid == 0) {
      __hip_atomic_fetch_add(&barG[t * 2], 1u, __ATOMIC_RELAXED, __HIP_MEMORY_SCOPE_AGENT);
      while (__hip_atomic_load(&barG[t * 2], __ATOMIC_RELAXED, __HIP_MEMORY_SCOPE_AGENT) < 32u)
        __builtin_amdgcn_s_sleep(1);
    }
    __syncthreads();

    // ---- stage h' (coalesced) -> act[:, 0:512] ----
    stage_tile(smem, Hb + parn * (256 * 512), 512, R0, 0, tid);
    __syncthreads();

    // ---- phase B (waves 0-5): acat = tanh(W1.h' + b); waves 6-7: do_outs(t-1) ----
    if (wave < 6) {
      f32x4 a3 = {0.f, 0.f, 0.f, 0.f};
#pragma unroll
      for (int kk = 0; kk < 16; ++kk) {
        bf16x8 av = actA(smem, rt3 * 16 + l15, kk * 32 + l16 * 8);
        a3 = __builtin_amdgcn_mfma_f32_16x16x32_bf16(av, bfrB[kk], a3, 0, 0, 0);
      }
      short* aout = Ab + parn * (256 * 1536);
#pragma unroll
      for (int r = 0; r < 4; ++r) {
        const float v = tanhf(a3[r] + bbB);
        const float vp = __shfl_xor(v, 1);
        if ((l15 & 1) == 0) {
          const unsigned pv = (unsigned)f2bu(v) | ((unsigned)f2bu(vp) << 16);
          st4c(aout + (size_t)(R0 + rt3 * 16 + l16 * 4 + r) * 1536 + cb + l15, pv);
        }
      }
    } else if (t > 0 && lb < 17) {
      do_outs(t - 1, Ab + par * (256 * 1536), R0, wave - 6, l15, l16, lb, W2T, b2cat,
              bsarr, offarr, out, N);
    }

    // ---- barrier B ----
    __syncthreads();
    if (tid == 0) {
      __hip_atomic_fetch_add(&barG[t * 2 + 1], 1u, __ATOMIC_RELAXED, __HIP_MEMORY_SCOPE_AGENT);
      while (__hip_atomic_load(&barG[t * 2 + 1], __ATOMIC_RELAXED, __HIP_MEMORY_SCOPE_AGENT) < 32u)
        __builtin_amdgcn_s_sleep(1);
    }
    __syncthreads();

    // ---- stage a1 (coalesced) -> act[:, 512:1024] ----
    stage_tile(smem, Ab + parn * (256 * 1536), 1536, R0, 1024, tid);
    __syncthreads();
  }

  // epilogue: outputs for final step
  if (lb < 17 && wave >= 6)
    do_outs(Lg - 1, Ab + (Lg & 1) * (256 * 1536), R0, wave - 6, l15, l16, lb, W2T, b2cat,
            bsarr, offarr, out, N);
}

// ---------------- host ----------------
extern "C" void kernel_launch(void* const* d_in, const int* in_sizes, int n_in,
                              void* d_out, int out_size, void* d_ws, size_t ws_size,
                              hipStream_t stream) {
  const float* features = (const float*)d_in[0];
  const int* lengths = (const int*)d_in[1];
  const float* Wf2h = (const float*)d_in[2];
  const float* bf2h_ = (const float*)d_in[3];
  const float* Wih = (const float*)d_in[4];
  const float* Whh = (const float*)d_in[5];
  const float* bih = (const float*)d_in[6];
  const float* bhh = (const float*)d_in[7];
  const float* p1W1 = (const float*)d_in[8];
  const float* p1b1 = (const float*)d_in[9];
  const float* p1W2 = (const float*)d_in[10];
  const float* p1b2 = (const float*)d_in[11];
  const float* p2W1 = (const float*)d_in[12];
  const float* p2b1 = (const float*)d_in[13];
  const float* p2W2 = (const float*)d_in[14];
  const float* p2b2 = (const float*)d_in[15];
  const float* oW1 = (const float*)d_in[16];
  const float* ob1 = (const float*)d_in[17];
  const float* oW2 = (const float*)d_in[18];
  const float* ob2 = (const float*)d_in[19];

  char* ws = (char*)d_ws;
  float* outp = (float*)d_out;
  int N = out_size / 385;

  hipMemsetAsync(ws + WS_BAR, 0, 32768, stream);
  k_fold<<<2048, 256, 0, stream>>>(ws, Wih, Whh, bih, bhh, p1W2, p1b2);
  k_w1t<<<1536, 256, 0, stream>>>(ws, p1W1, p1b1, p2W1, p2b1, oW1, ob1);
  k_w2t<<<272, 256, 0, stream>>>(ws, p1W2, p1b2, p2W2, p2b2, oW2, ob2);
  k_h0c0<<<256, 256, 0, stream>>>(ws, features, Wf2h, bf2h_);
  k_bs<<<1, 512, 0, stream>>>(ws, lengths);

  hipFuncSetAttribute((const void*)scan_kernel,
                      hipFuncAttributeMaxDynamicSharedMemorySize, DYN_LDS);

  const int* lenv = lengths;
  void* args[] = {&ws, &lenv, &outp, &N};
  hipLaunchCooperativeKernel((const void*)scan_kernel, dim3(NBLK), dim3(NTHR),
                             args, DYN_LDS, stream);
}